// Round 8
// baseline (1551.481 us; speedup 1.0000x reference)
//
#include <hip/hip_runtime.h>
#include <math.h>
#include <stdint.h>

#define E_N 19
#define H_N 32
#define T_N 2048
#define B_N 64
#define G_N 128      // 4*H gate rows per chain
#define LOG2E 1.4426950408889634f

typedef _Float16 f16x8 __attribute__((ext_vector_type(8)));
typedef float    f32x4 __attribute__((ext_vector_type(4)));

__device__ __forceinline__ float sigm_rcp(float e) {  // 1/(1+e)
    return __builtin_amdgcn_rcpf(1.0f + e);
}

// MFMA-batched LSTM: one WAVE per (e, d, batch-group of 16).
// Per step: gates(128x16) = W_hh(128x32) @ H(32x16) as 8x mfma_f32_16x16x32_f16.
//
// Layout theorem (why there are ZERO cross-lane ops):
//   C/D frag (verified m89): col = lane&15, row_in_tile = (lane>>4)*4 + reg.
//   A frag: row = lane&15, k = (lane>>4)*8 + j.   B frag: col = lane&15,
//   k = (lane>>4)*8 + j.
//   Assign gate row (tile m, tile-row t) -> W row 32*(m>>1) + dim(m,t),
//   dim(m,t) = 8*(t>>2) + (t&3) + 4*(m&1); tiles 0,1=i 2,3=f 4,5=g 6,7=o.
//   Then lane (q, col) holds all 4 gates for h-dims 8q..8q+7 of chain col
//   (c,h update lane-local), and the NEXT step's B fragment needs exactly
//   h[8q..8q+7] of chain col == the lane's own h. B = cvt(h[0..7]). Done.
//
// Activation scales (-LOG2E for i,f,o rows; -2*LOG2E for g rows) are folded
// into the f16 weights + bias + w_ih at load time, so each gate is just
// exp2 -> add 1 -> rcp (-> fma for tanh).
//
// waves_per_eu(1,1): 512-VGPR license for the ~175-reg live set; residency
// cap (4 blocks/CU) is irrelevant at 152 blocks on 256 CUs (<=1/CU).
__global__ __launch_bounds__(64)
__attribute__((amdgpu_waves_per_eu(1, 1)))
void lstm_mfma_kernel(
    const float* __restrict__ x,     // [B, T, E]
    const float* __restrict__ w_ih,  // [E, 2, 4H]
    const float* __restrict__ w_hh,  // [E, 2, 4H, H]
    const float* __restrict__ b_ih,  // [E, 2, 4H]
    const float* __restrict__ b_hh,  // [E, 2, 4H]
    float* __restrict__ hT)          // [B, E, 2, H]
{
    const int lane = threadIdx.x;
    const int blk  = blockIdx.x;          // ed*4 + g
    const int ed   = blk >> 2;            // e*2 + d
    const int g    = blk & 3;
    const int e    = ed >> 1;
    const int d    = ed & 1;
    const int q    = lane >> 4;
    const int col  = lane & 15;
    const int b    = g * 16 + col;

    // ---- static per-lane data: A fragments + C-init constants (pre-scaled) ----
    const float* whh = w_hh + (size_t)ed * G_N * H_N;
    f16x8 av[8];
    float biasv[32], wihv[32];
    #pragma unroll
    for (int m = 0; m < 8; ++m) {
        const float sc = ((m >> 1) == 2) ? (-2.0f * LOG2E) : (-LOG2E);
        // A: row t = col, k = q*8 + j
        {
            const int t   = col;
            const int row = 32 * (m >> 1) + 8 * (t >> 2) + (t & 3) + 4 * (m & 1);
            const float* wr = whh + (size_t)row * H_N + q * 8;
            #pragma unroll
            for (int j = 0; j < 8; ++j) av[m][j] = (_Float16)(wr[j] * sc);
        }
        // C-init constants: C row_in_tile = q*4 + r -> dim 8q + r + 4*(m&1)
        #pragma unroll
        for (int r = 0; r < 4; ++r) {
            const int row = 32 * (m >> 1) + 8 * q + r + 4 * (m & 1);
            biasv[m * 4 + r] = (b_ih[(size_t)ed * G_N + row] +
                                b_hh[(size_t)ed * G_N + row]) * sc;
            wihv[m * 4 + r]  = w_ih[(size_t)ed * G_N + row] * sc;
        }
    }

    // state: c and h for dims 8q..8q+7 of chain col (all lane-local)
    float cst[8], hout[8];
    f16x8 bfrag;
    #pragma unroll
    for (int dd = 0; dd < 8; ++dd) {
        cst[dd] = 0.0f; hout[dd] = 0.0f; bfrag[dd] = (_Float16)0.0f;
    }

    // x staging: each lane reads its own chain's x, 4 steps double-buffered
    const float* xb = x + (size_t)b * T_N * E_N + e;
    float xc[4], xn[4];
    #pragma unroll
    for (int s = 0; s < 4; ++s) {
        const int tp = d ? (T_N - 1 - s) : s;
        xc[s] = xb[(size_t)tp * E_N];
    }

    #pragma unroll 1
    for (int t0 = 0; t0 < T_N; t0 += 4) {
        if (t0 + 4 < T_N) {
            #pragma unroll
            for (int s = 0; s < 4; ++s) {
                const int tn = t0 + 4 + s;
                const int tp = d ? (T_N - 1 - tn) : tn;
                xn[s] = xb[(size_t)tp * E_N];
            }
        }
        #pragma unroll
        for (int s = 0; s < 4; ++s) {
            const float xv = xc[s];
            // C init: bias' + w_ih' * x  (pre-scaled)
            f32x4 C[8];
            #pragma unroll
            for (int m = 0; m < 8; ++m)
                #pragma unroll
                for (int r = 0; r < 4; ++r)
                    C[m][r] = fmaf(wihv[m * 4 + r], xv, biasv[m * 4 + r]);
            // gates += W_hh' @ h   (8 MFMAs, B = lane-local h fp16)
            #pragma unroll
            for (int m = 0; m < 8; ++m)
                C[m] = __builtin_amdgcn_mfma_f32_16x16x32_f16(av[m], bfrag, C[m], 0, 0, 0);
            // activations: i,f,o -> sigmoid; g (m=4,5) -> tanh
            #pragma unroll
            for (int m = 0; m < 8; ++m) {
                #pragma unroll
                for (int r = 0; r < 4; ++r) {
                    const float sg = sigm_rcp(__builtin_amdgcn_exp2f(C[m][r]));
                    C[m][r] = (m == 4 || m == 5) ? fmaf(2.0f, sg, -1.0f) : sg;
                }
            }
            // c,h update (all lane-local): dim dd -> tile pair index hi, reg r
            #pragma unroll
            for (int dd = 0; dd < 8; ++dd) {
                const int hi = dd >> 2, r = dd & 3;
                const float si = C[0 + hi][r];
                const float sf = C[2 + hi][r];
                const float tg = C[4 + hi][r];
                const float so = C[6 + hi][r];
                cst[dd] = fmaf(sf, cst[dd], si * tg);
                const float tc = fmaf(2.0f, sigm_rcp(
                    __builtin_amdgcn_exp2f(cst[dd] * (-2.0f * LOG2E))), -1.0f);
                hout[dd] = so * tc;
            }
            // next B fragment = own h, quantized (RTN casts)
            #pragma unroll
            for (int dd = 0; dd < 8; ++dd) bfrag[dd] = (_Float16)hout[dd];
        }
        #pragma unroll
        for (int s = 0; s < 4; ++s) xc[s] = xn[s];
    }

    // final h: dims 8q..8q+7 of chain (b, e, d), full f32
    float* dst = hT + (((size_t)(b * E_N + e)) * 2 + d) * H_N + 8 * q;
    #pragma unroll
    for (int dd = 0; dd < 8; ++dd) dst[dd] = hout[dd];
}

// LayerNorm over 64 feats per (b,e), mean over e, FC -> out[b]. One wave per b.
__global__ __launch_bounds__(64) void head_kernel(
    const float* __restrict__ hT,      // [B, E, 64]
    const float* __restrict__ ln_gamma,// [E, 64]
    const float* __restrict__ ln_beta, // [E, 64]
    const float* __restrict__ fc_w,    // [64]
    const float* __restrict__ fc_b,    // [1]
    float* __restrict__ out)           // [B]
{
    const int b = blockIdx.x;
    const int f = threadIdx.x; // 0..63

    float acc = 0.0f;
    for (int e = 0; e < E_N; ++e) {
        const float v = hT[(size_t)(b * E_N + e) * 64 + f];
        float s = v, s2 = v * v;
        #pragma unroll
        for (int off = 32; off > 0; off >>= 1) {
            s  += __shfl_xor(s,  off);
            s2 += __shfl_xor(s2, off);
        }
        const float mean = s * (1.0f / 64.0f);
        const float var  = s2 * (1.0f / 64.0f) - mean * mean;
        const float inv  = rsqrtf(var + 1e-5f);
        acc += (v - mean) * inv * ln_gamma[e * 64 + f] + ln_beta[e * 64 + f];
    }
    float contrib = (acc * (1.0f / (float)E_N)) * fc_w[f];
    #pragma unroll
    for (int off = 32; off > 0; off >>= 1) contrib += __shfl_xor(contrib, off);
    if (f == 0) out[b] = contrib + fc_b[0];
}

extern "C" void kernel_launch(void* const* d_in, const int* in_sizes, int n_in,
                              void* d_out, int out_size, void* d_ws, size_t ws_size,
                              hipStream_t stream) {
    const float* x        = (const float*)d_in[0];
    const float* w_ih     = (const float*)d_in[1];
    const float* w_hh     = (const float*)d_in[2];
    const float* b_ih     = (const float*)d_in[3];
    const float* b_hh     = (const float*)d_in[4];
    const float* ln_gamma = (const float*)d_in[5];
    const float* ln_beta  = (const float*)d_in[6];
    const float* fc_w     = (const float*)d_in[7];
    const float* fc_b     = (const float*)d_in[8];
    float* out = (float*)d_out;
    float* hT  = (float*)d_ws;  // B*E*2*H floats

    lstm_mfma_kernel<<<E_N * 2 * 4, 64, 0, stream>>>(x, w_ih, w_hh, b_ih, b_hh, hT);
    head_kernel<<<B_N, 64, 0, stream>>>(hT, ln_gamma, ln_beta, fc_w, fc_b, out);
}

// Round 9
// 951.462 us; speedup vs baseline: 1.6306x; 1.6306x over previous
//
#include <hip/hip_runtime.h>
#include <math.h>
#include <stdint.h>

#define E_N 19
#define H_N 32
#define T_N 2048
#define B_N 64
#define G_N 128      // 4*H gate rows per chain
#define XCHUNK 32    // timesteps staged per LDS round (per direction)
#define LOG2E 1.4426950408889634f

typedef _Float16 half2_t __attribute__((ext_vector_type(2)));

__device__ __forceinline__ float sigm_rcp(float e) {  // 1/(1+e)
    return __builtin_amdgcn_rcpf(1.0f + e);
}

// One WAVE (64-thread block) per (b,e). TWO chains per wave:
//   lanes 0..31  : direction 0 (forward time),  j = lane
//   lanes 32..63 : direction 1 (reversed time), j = lane-32
// Each lane owns ALL FOUR gate rows {i_j, f_j, g_j, o_j} of its chain:
//   - no cross-lane exchange at all (c,h update fully lane-local)
//   - activations stay LANE-VECTORIZED (6 trans instrs serve all 32 dims x
//     2 chains) — the R8 MFMA kernel lost exactly this and paid 80 trans/step
//   - per-chain issue ~145 cy vs 278 for the 1-chain/wave structure
// h broadcast via LDS: every lane writes its h (slot = lane); each 32-lane half
// re-reads its chain's 32 packed fp16 h as 4x ds_read_b128 (same address within
// each half -> broadcast; halves hit disjoint 64B regions -> conflict-free).
//
// REGISTER LICENSE — waves_per_eu(2,2), the untested cell that closes both
// failure modes seen in R2-R5:
//   min=2 -> VGPR cap 512/2=256: live set ~110 fits with slack ((1,1) proved
//            the allocator will use 130+ when licensed; (3,3)/(4,4)/open-max
//            all starved it to 52-72 and re-loaded weights from global every
//            chunk: FETCH 61-64 MB vs the ideal 40 MB).
//   max=2 -> residency cap 2 waves/EU = 8 blocks/CU >= the 4.75 blocks/CU
//            demand -> ONE pass ((1,1)'s max=1 forced 4/CU -> two sequential
//            passes, dur 2x).
__global__ __launch_bounds__(64)
__attribute__((amdgpu_waves_per_eu(2, 2)))
void lstm_chain_kernel(
    const float* __restrict__ x,     // [B, T, E]
    const float* __restrict__ w_ih,  // [E, 2, 4H]
    const float* __restrict__ w_hh,  // [E, 2, 4H, H]
    const float* __restrict__ b_ih,  // [E, 2, 4H]
    const float* __restrict__ b_hh,  // [E, 2, 4H]
    float* __restrict__ hT)          // [B, E, 2, H]
{
    const int lane = threadIdx.x;
    const int be   = blockIdx.x;          // b*E + e
    const int b    = be / E_N;
    const int e    = be - b * E_N;
    const int j    = lane & 31;
    const int half = lane >> 5;           // == direction d
    const int ed   = e * 2 + half;

    // ---- load fp32 weights for rows j, j+32, j+64, j+96 (i,f,g,o), pack fp16 ----
    const float* wbase = w_hh + (size_t)ed * G_N * H_N;
    uint32_t wp[4][16];                   // 64 VGPRs of packed fp16 weight pairs
    #pragma unroll
    for (int r = 0; r < 4; ++r) {
        const float* wr = wbase + (size_t)(j + 32 * r) * H_N;
        #pragma unroll
        for (int m = 0; m < 16; ++m) {
            float2 v = ((const float2*)wr)[m];
            half2_t p = { (_Float16)v.x, (_Float16)v.y };
            wp[r][m] = __builtin_bit_cast(uint32_t, p);
        }
    }
    float wih[4], bias[4];
    #pragma unroll
    for (int r = 0; r < 4; ++r) {
        const int row = j + 32 * r;
        wih[r]  = w_ih[(size_t)ed * G_N + row];
        bias[r] = b_ih[(size_t)ed * G_N + row] + b_hh[(size_t)ed * G_N + row];
    }

    // LDS: h (64 fp16: [0..31] chain d0, [32..63] chain d1) + x chunk per dir
    __shared__ __align__(16) uint16_t hbuf[64];
    __shared__ float xbuf[64];            // [0..31] fwd steps, [32..63] rev steps

    hbuf[lane] = 0;
    float c = 0.0f, h = 0.0f;

    const float* xbase = x + (size_t)b * T_N * E_N + e;

    // prefetch first x chunk: this half's step t = j (physical index per dir)
    float xreg;
    {
        const int tphys = half ? (T_N - 1 - j) : j;
        xreg = xbase[(size_t)tphys * E_N];
    }

    for (int t0 = 0; t0 < T_N; t0 += XCHUNK) {
        // PIN: keep the 64 packed weight regs live across the inner loop (no-op).
        #pragma unroll
        for (int r = 0; r < 4; ++r)
            #pragma unroll
            for (int m = 0; m < 16; ++m)
                asm volatile("" : "+v"(wp[r][m]));

        // stage this chunk (already in xreg), then issue next chunk's global load
        xbuf[lane] = xreg;
        if (t0 + XCHUNK < T_N) {
            const int tn    = t0 + XCHUNK + j;
            const int tphys = half ? (T_N - 1 - tn) : tn;
            xreg = xbase[(size_t)tphys * E_N];
        }

        #pragma unroll 1
        for (int tl = 0; tl < XCHUNK; ++tl) {
            // broadcast reads: this half's 32 h fp16 (4 x b128) + x (b32)
            const uint4 q0 = ((const uint4*)hbuf)[half * 4 + 0];
            const uint4 q1 = ((const uint4*)hbuf)[half * 4 + 1];
            const uint4 q2 = ((const uint4*)hbuf)[half * 4 + 2];
            const uint4 q3 = ((const uint4*)hbuf)[half * 4 + 3];
            const float sx = xbuf[(half << 5) + tl];

            uint32_t hp[16];
            hp[0]=q0.x; hp[1]=q0.y; hp[2]=q0.z; hp[3]=q0.w;
            hp[4]=q1.x; hp[5]=q1.y; hp[6]=q1.z; hp[7]=q1.w;
            hp[8]=q2.x; hp[9]=q2.y; hp[10]=q2.z; hp[11]=q2.w;
            hp[12]=q3.x; hp[13]=q3.y; hp[14]=q3.z; hp[15]=q3.w;

            // 4 gate dots, each split 2 x 8-deep (8 independent fdot2 chains)
            float acc[4], accb[4];
            #pragma unroll
            for (int r = 0; r < 4; ++r) {
                acc[r]  = fmaf(sx, wih[r], bias[r]);
                accb[r] = 0.0f;
            }
            #pragma unroll
            for (int m = 0; m < 8; ++m) {
                #pragma unroll
                for (int r = 0; r < 4; ++r) {
                    acc[r]  = __builtin_amdgcn_fdot2(
                        __builtin_bit_cast(half2_t, hp[m]),
                        __builtin_bit_cast(half2_t, wp[r][m]),   acc[r],  false);
                    accb[r] = __builtin_amdgcn_fdot2(
                        __builtin_bit_cast(half2_t, hp[m + 8]),
                        __builtin_bit_cast(half2_t, wp[r][m + 8]), accb[r], false);
                }
            }
            const float gi = acc[0] + accb[0];
            const float gf = acc[1] + accb[1];
            const float gg = acc[2] + accb[2];
            const float go = acc[3] + accb[3];

            // activations (PyTorch gate order i,f,g,o) — lane-vectorized:
            // 8 trans instrs serve 32 dims x 2 chains
            const float si = sigm_rcp(__builtin_amdgcn_exp2f(gi * (-LOG2E)));
            const float sf = sigm_rcp(__builtin_amdgcn_exp2f(gf * (-LOG2E)));
            const float tg = fmaf(2.0f, sigm_rcp(
                __builtin_amdgcn_exp2f(gg * (-2.0f * LOG2E))), -1.0f);   // tanh(g)
            const float so = sigm_rcp(__builtin_amdgcn_exp2f(go * (-LOG2E)));

            c = fmaf(sf, c, si * tg);                                    // f*c + i*g
            const float tc = fmaf(2.0f, sigm_rcp(
                __builtin_amdgcn_exp2f(c * (-2.0f * LOG2E))), -1.0f);    // tanh(c)
            h = so * tc;                                                 // o * tanh(c)

            // publish h: slot = lane (b16 write, conflict-free)
            hbuf[lane] = __builtin_bit_cast(uint16_t, (_Float16)h);
        }
    }

    // every lane holds a valid final h for its (chain, j)
    hT[((size_t)(b * E_N + e) * 2 + half) * H_N + j] = h;
}

// LayerNorm over 64 feats per (b,e), mean over e, FC -> out[b]. One wave per b.
__global__ __launch_bounds__(64) void head_kernel(
    const float* __restrict__ hT,      // [B, E, 64]
    const float* __restrict__ ln_gamma,// [E, 64]
    const float* __restrict__ ln_beta, // [E, 64]
    const float* __restrict__ fc_w,    // [64]
    const float* __restrict__ fc_b,    // [1]
    float* __restrict__ out)           // [B]
{
    const int b = blockIdx.x;
    const int f = threadIdx.x; // 0..63

    float acc = 0.0f;
    for (int e = 0; e < E_N; ++e) {
        const float v = hT[(size_t)(b * E_N + e) * 64 + f];
        float s = v, s2 = v * v;
        #pragma unroll
        for (int off = 32; off > 0; off >>= 1) {
            s  += __shfl_xor(s,  off);
            s2 += __shfl_xor(s2, off);
        }
        const float mean = s * (1.0f / 64.0f);
        const float var  = s2 * (1.0f / 64.0f) - mean * mean;
        const float inv  = rsqrtf(var + 1e-5f);
        acc += (v - mean) * inv * ln_gamma[e * 64 + f] + ln_beta[e * 64 + f];
    }
    float contrib = (acc * (1.0f / (float)E_N)) * fc_w[f];
    #pragma unroll
    for (int off = 32; off > 0; off >>= 1) contrib += __shfl_xor(contrib, off);
    if (f == 0) out[b] = contrib + fc_b[0];
}

extern "C" void kernel_launch(void* const* d_in, const int* in_sizes, int n_in,
                              void* d_out, int out_size, void* d_ws, size_t ws_size,
                              hipStream_t stream) {
    const float* x        = (const float*)d_in[0];
    const float* w_ih     = (const float*)d_in[1];
    const float* w_hh     = (const float*)d_in[2];
    const float* b_ih     = (const float*)d_in[3];
    const float* b_hh     = (const float*)d_in[4];
    const float* ln_gamma = (const float*)d_in[5];
    const float* ln_beta  = (const float*)d_in[6];
    const float* fc_w     = (const float*)d_in[7];
    const float* fc_b     = (const float*)d_in[8];
    float* out = (float*)d_out;
    float* hT  = (float*)d_ws;  // B*E*2*H floats

    lstm_chain_kernel<<<B_N * E_N, 64, 0, stream>>>(x, w_ih, w_hh, b_ih, b_hh, hT);
    head_kernel<<<B_N, 64, 0, stream>>>(hT, ln_gamma, ln_beta, fc_w, fc_b, out);
}